// Round 6
// baseline (783.643 us; speedup 1.0000x reference)
//
#include <hip/hip_runtime.h>
#include <math.h>

// RALALinearAttention on MI355X — round 6.
// r5 bug: staging kept a +i*64 row loop after switching to one-row-per-thread
// (rows ran to 191, corrupting the next LDS buffer). Fixed: single-pass
// staging, 256 threads x 16 f16 = exactly one 128x32 tile per buffer.
constexpr int B   = 16;
constexpr int IH  = 64;
constexpr int IW  = 64;
constexpr int C   = 256;
constexpr int NH  = 8;
constexpr int HD  = 32;
constexpr int N   = IH * IW;    // 4096
constexpr int C4  = 4 * C;      // 1024

using f16x8 = __attribute__((ext_vector_type(8))) _Float16;
using f16x4 = __attribute__((ext_vector_type(4))) _Float16;
using f32x4 = __attribute__((ext_vector_type(4))) float;

// ---------------------------------------------------------------- tables ----
__global__ void k_tables(float* __restrict__ cosT, float* __restrict__ sinT) {
  int t = blockIdx.x * 256 + threadIdx.x;      // N*16 = 65536
  int j = t & 15, pix = t >> 4;
  int y = pix >> 6, x = pix & 63;
  int jj = j & 7;
  double theta = pow(10000.0, -(double)jj / 8.0);
  double pos = (j < 8) ? (double)y : (double)x;
  double ang = pos * theta;
  cosT[t] = (float)cos(ang);
  sinT[t] = (float)sin(ang);
}

// -------------------- split f32 -> (hi,lo) f16, same layout -----------------
__global__ void k_split_x(const float* __restrict__ src, _Float16* __restrict__ hi,
                          _Float16* __restrict__ lo, int total4) {
  int i = blockIdx.x * 256 + threadIdx.x;
  if (i >= total4) return;
  float4 v = reinterpret_cast<const float4*>(src)[i];
  float vv[4] = {v.x, v.y, v.z, v.w};
  f16x4 h, l;
#pragma unroll
  for (int j = 0; j < 4; ++j) {
    _Float16 hh = (_Float16)vv[j];
    h[j] = hh;
    l[j] = (_Float16)(vv[j] - (float)hh);
  }
  reinterpret_cast<f16x4*>(hi)[i] = h;
  reinterpret_cast<f16x4*>(lo)[i] = l;
}

// ------------- split weight [K=256][ldb] -> transposed [ldb][256] -----------
__global__ void k_split_wT(const float* __restrict__ w, int ldb,
                           _Float16* __restrict__ hiT, _Float16* __restrict__ loT) {
  int n = blockIdx.x;           // column of w
  int k = threadIdx.x;          // 0..255
  float v = w[(size_t)k * ldb + n];
  _Float16 h = (_Float16)v;
  hiT[(size_t)n * 256 + k] = h;
  loT[(size_t)n * 256 + k] = (_Float16)(v - (float)h);
}

// --------------- split-f16 MFMA GEMM: C = A(f32-equiv) @ B + bias -----------
// 128x128 tile, 4 waves (2x2), K=256, BK=32, 3-product Ootomo split.
// A: preconverted (AhG/AlG f16 [M][lda]) or f32 (Af32, converted in staging).
// B: preconverted transposed splits [N][256].
// Epilogue: LDS transpose -> float4-coalesced C stores. nelu: elu+1 columns.
__global__ __launch_bounds__(256) void k_gemm_split(
    const _Float16* __restrict__ AhG, const _Float16* __restrict__ AlG,
    const float* __restrict__ Af32, int lda,
    const _Float16* __restrict__ BhT, const _Float16* __restrict__ BlT,
    const float* __restrict__ bias, float* __restrict__ Cm, int ldc,
    int nelu) {
  __shared__ _Float16 lds[4 * 5120];          // Ah | Al | Bh | Bl, stride 40
  _Float16* AhL = lds;
  _Float16* AlL = lds + 5120;
  _Float16* BhL = lds + 10240;
  _Float16* BlL = lds + 15360;
  int t = threadIdx.x;
  int m0 = blockIdx.x * 128, n0 = blockIdx.y * 128;
  int lane = t & 63;
  int wm = t >> 7, wn = (t >> 6) & 1;
  int lr = lane & 15, lg = lane >> 4;
  int srow = t >> 1, sseg = t & 1;            // one row-half per thread

  f32x4 acc[4][4] = {};

  for (int kc = 0; kc < 256; kc += 32) {
    // ---- stage A (128 rows x 32 k): 256 threads x 16 f16 = full tile ----
    if (Af32) {
      const float* ap = &Af32[(size_t)(m0 + srow) * lda + kc + sseg * 16];
      f16x8 h0, h1, l0, l1;
#pragma unroll
      for (int j = 0; j < 8; ++j) {
        float v = ap[j];
        _Float16 h = (_Float16)v;
        h0[j] = h; l0[j] = (_Float16)(v - (float)h);
        float v2 = ap[j + 8];
        _Float16 h2 = (_Float16)v2;
        h1[j] = h2; l1[j] = (_Float16)(v2 - (float)h2);
      }
      int d = srow * 40 + sseg * 16;
      *(f16x8*)&AhL[d] = h0; *(f16x8*)&AhL[d + 8] = h1;
      *(f16x8*)&AlL[d] = l0; *(f16x8*)&AlL[d + 8] = l1;
    } else {
      size_t g = (size_t)(m0 + srow) * lda + kc + sseg * 16;
      f16x8 h0 = *(const f16x8*)&AhG[g];
      f16x8 h1 = *(const f16x8*)&AhG[g + 8];
      f16x8 l0 = *(const f16x8*)&AlG[g];
      f16x8 l1 = *(const f16x8*)&AlG[g + 8];
      int d = srow * 40 + sseg * 16;
      *(f16x8*)&AhL[d] = h0; *(f16x8*)&AhL[d + 8] = h1;
      *(f16x8*)&AlL[d] = l0; *(f16x8*)&AlL[d + 8] = l1;
    }
    // ---- stage B (128 cols x 32 k) from transposed splits ----
    {
      size_t g = (size_t)(n0 + srow) * 256 + kc + sseg * 16;
      f16x8 h0 = *(const f16x8*)&BhT[g];
      f16x8 h1 = *(const f16x8*)&BhT[g + 8];
      f16x8 l0 = *(const f16x8*)&BlT[g];
      f16x8 l1 = *(const f16x8*)&BlT[g + 8];
      int d = srow * 40 + sseg * 16;
      *(f16x8*)&BhL[d] = h0; *(f16x8*)&BhL[d + 8] = h1;
      *(f16x8*)&BlL[d] = l0; *(f16x8*)&BlL[d + 8] = l1;
    }
    __syncthreads();

    // ---- fragments + 48 MFMA ----
    f16x8 ah[4], al[4];
#pragma unroll
    for (int mi = 0; mi < 4; ++mi) {
      int ar = (wm * 64 + mi * 16 + lr) * 40 + lg * 8;
      ah[mi] = *(const f16x8*)&AhL[ar];
      al[mi] = *(const f16x8*)&AlL[ar];
    }
#pragma unroll
    for (int ni = 0; ni < 4; ++ni) {
      int br = (wn * 64 + ni * 16 + lr) * 40 + lg * 8;
      f16x8 bh = *(const f16x8*)&BhL[br];
      f16x8 bl = *(const f16x8*)&BlL[br];
#pragma unroll
      for (int mi = 0; mi < 4; ++mi) {
        acc[mi][ni] = __builtin_amdgcn_mfma_f32_16x16x32_f16(ah[mi], bh, acc[mi][ni], 0, 0, 0);
        acc[mi][ni] = __builtin_amdgcn_mfma_f32_16x16x32_f16(al[mi], bh, acc[mi][ni], 0, 0, 0);
        acc[mi][ni] = __builtin_amdgcn_mfma_f32_16x16x32_f16(ah[mi], bl, acc[mi][ni], 0, 0, 0);
      }
    }
    __syncthreads();
  }

  // ---- epilogue: LDS transpose -> coalesced float4 stores ----
  float* Cl = reinterpret_cast<float*>(lds);   // 32 x 132 f32 = 16.9 KB
  int ri2 = t >> 3, c0 = (t & 7) << 4;
#pragma unroll
  for (int mi = 0; mi < 4; ++mi) {
#pragma unroll
    for (int ni = 0; ni < 4; ++ni) {
      int col = wn * 64 + ni * 16 + lr;
#pragma unroll
      for (int r = 0; r < 4; ++r)
        Cl[(wm * 16 + lg * 4 + r) * 132 + col] = acc[mi][ni][r];
    }
    __syncthreads();
    int grow = m0 + (ri2 >> 4) * 64 + mi * 16 + (ri2 & 15);
#pragma unroll
    for (int j = 0; j < 4; ++j) {
      int col = n0 + c0 + j * 4;
      float4 v = *(const float4*)&Cl[ri2 * 132 + c0 + j * 4];
      float4 bb = *(const float4*)&bias[col];
      v.x += bb.x; v.y += bb.y; v.z += bb.z; v.w += bb.w;
      if (col < nelu) {
        v.x = (v.x > 0.f) ? v.x + 1.f : expf(v.x);
        v.y = (v.y > 0.f) ? v.y + 1.f : expf(v.y);
        v.z = (v.z > 0.f) ? v.z + 1.f : expf(v.z);
        v.w = (v.w > 0.f) ? v.w + 1.f : expf(v.w);
      }
      *(float4*)&Cm[(size_t)grow * ldc + col] = v;
    }
    __syncthreads();
  }
}

// ---------------- column-mean over n, stage 1: per-(bh,chunk) partials ------
__global__ __launch_bounds__(256) void k_colmean_part(
    const float* __restrict__ qkvo, const float* __restrict__ effN,
    float* __restrict__ part, int colbase) {
  int bh = blockIdx.x, chunk = blockIdx.y;
  int b = bh >> 3, h = bh & 7;
  int t = threadIdx.x;
  int d = t & 31, r = t >> 5;                  // 8 rows in flight
  size_t base = (size_t)b * N * C4 + colbase + (h << 5) + d;
  int n0 = chunk << 8;
  float acc = 0.f;
  for (int n = n0 + r; n < n0 + 256; n += 8) {
    float v = qkvo[base + (size_t)n * C4];
    if (effN) v *= effN[(size_t)bh * N + n];
    acc += v;
  }
  __shared__ float sm[256];
  sm[t] = acc;
  __syncthreads();
  if (t < 32) {
    float s = 0.f;
#pragma unroll
    for (int rr = 0; rr < 8; ++rr) s += sm[rr * 32 + t];
    part[(size_t)((bh << 4) + chunk) * 32 + t] = s;
  }
}

// ---------------- column-mean stage 2: combine 16 chunk partials ------------
__global__ void k_colmean_fin(const float* __restrict__ part,
                              float* __restrict__ outm, int total) {
  int i = blockIdx.x * 256 + threadIdx.x;      // bpp*NH*32
  if (i >= total) return;
  int bh = i >> 5, d = i & 31;
  float s = 0.f;
#pragma unroll
  for (int c = 0; c < 16; ++c) s += part[(size_t)((bh << 4) + c) * 32 + d];
  outm[i] = s * (1.0f / N);
}

// ------------------------------------------- scores s = scale * qmean.k -----
__global__ void k_scores(const float* __restrict__ qkvo,
                         const float* __restrict__ qmean, float* __restrict__ s) {
  int tid = blockIdx.x * 256 + threadIdx.x;   // bpp*NH*N
  int n = tid & (N - 1);
  int bh = tid >> 12;
  int b = bh >> 3, h = bh & 7;
  const float* kp = &qkvo[(size_t)(b * N + n) * C4 + 256 + (h << 5)];
  const float* qm = &qmean[bh << 5];
  float dot = 0.f;
#pragma unroll
  for (int i = 0; i < 8; ++i) {
    float4 k4 = *reinterpret_cast<const float4*>(&kp[i << 2]);
    float4 q4 = *reinterpret_cast<const float4*>(&qm[i << 2]);
    dot += k4.x * q4.x + k4.y * q4.y + k4.z * q4.z + k4.w * q4.w;
  }
  s[tid] = dot * 0.1767766952966369f;         // 32^-0.5
}

// ------------- softmax over n (LDS-cached row), fold *N (eff -> eff*N) ------
__global__ __launch_bounds__(256) void k_softmax(float* __restrict__ s) {
  __shared__ float rowl[N];
  __shared__ float red[256];
  int bh = blockIdx.x;
  int t = threadIdx.x;
  float* row = s + (size_t)bh * N;
  float mx = -3.4e38f;
  for (int i = t; i < N / 4; i += 256) {
    float4 v = reinterpret_cast<const float4*>(row)[i];
    reinterpret_cast<float4*>(rowl)[i] = v;
    mx = fmaxf(mx, fmaxf(fmaxf(v.x, v.y), fmaxf(v.z, v.w)));
  }
  red[t] = mx; __syncthreads();
  for (int off = 128; off > 0; off >>= 1) {
    if (t < off) red[t] = fmaxf(red[t], red[t + off]);
    __syncthreads();
  }
  mx = red[0]; __syncthreads();
  float sum = 0.f;
  for (int n = t; n < N; n += 256) {
    float e = expf(rowl[n] - mx);
    rowl[n] = e;
    sum += e;
  }
  red[t] = sum; __syncthreads();
  for (int off = 128; off > 0; off >>= 1) {
    if (t < off) red[t] += red[t + off];
    __syncthreads();
  }
  float scale = (float)N / red[0];
  for (int i = t; i < N / 4; i += 256) {
    float4 v = reinterpret_cast<const float4*>(rowl)[i];
    v.x *= scale; v.y *= scale; v.z *= scale; v.w *= scale;
    reinterpret_cast<float4*>(row)[i] = v;
  }
}

// ---------------- z + scale k by eff*N + RoPE(q,k) in place + write z -------
__global__ __launch_bounds__(256) void k_rope_z(
    float* __restrict__ qkvo, const float* __restrict__ effN,
    const float* __restrict__ kmean, const float* __restrict__ cosT,
    const float* __restrict__ sinT, float* __restrict__ z) {
  int tid = blockIdx.x * 256 + threadIdx.x;   // bpp*N*NH
  int h = tid & 7;
  int bn = tid >> 3;                          // pass-local row
  int n = bn & (N - 1);
  int b = bn >> 12;
  size_t qb = (size_t)bn * C4 + (h << 5);
  float q[32], k[32];
#pragma unroll
  for (int i = 0; i < 8; ++i) {
    float4 q4 = *reinterpret_cast<const float4*>(&qkvo[qb + (i << 2)]);
    float4 k4 = *reinterpret_cast<const float4*>(&qkvo[qb + 256 + (i << 2)]);
    q[i * 4 + 0] = q4.x; q[i * 4 + 1] = q4.y; q[i * 4 + 2] = q4.z; q[i * 4 + 3] = q4.w;
    k[i * 4 + 0] = k4.x; k[i * 4 + 1] = k4.y; k[i * 4 + 2] = k4.z; k[i * 4 + 3] = k4.w;
  }
  int bh = (b << 3) + h;
  const float* km = &kmean[bh << 5];
  float dot = 0.f;
#pragma unroll
  for (int dd = 0; dd < 32; ++dd) dot += q[dd] * km[dd];
  z[(size_t)bh * N + n] = 1.0f / (dot + 1e-6f);
  float ef = effN[(size_t)bh * N + n];
#pragma unroll
  for (int dd = 0; dd < 32; ++dd) k[dd] *= ef;
  const float* cp = &cosT[n << 4];
  const float* sp = &sinT[n << 4];
#pragma unroll
  for (int j = 0; j < 16; ++j) {
    float cc = cp[j], ss = sp[j];
    float qr = q[2 * j], qi = q[2 * j + 1];
    q[2 * j]     = qr * cc - qi * ss;
    q[2 * j + 1] = qr * ss + qi * cc;
    float kr = k[2 * j], ki = k[2 * j + 1];
    k[2 * j]     = kr * cc - ki * ss;
    k[2 * j + 1] = kr * ss + ki * cc;
  }
#pragma unroll
  for (int i = 0; i < 8; ++i) {
    float4 q4 = {q[i * 4 + 0], q[i * 4 + 1], q[i * 4 + 2], q[i * 4 + 3]};
    float4 k4 = {k[i * 4 + 0], k[i * 4 + 1], k[i * 4 + 2], k[i * 4 + 3]};
    *reinterpret_cast<float4*>(&qkvo[qb + (i << 2)]) = q4;
    *reinterpret_cast<float4*>(&qkvo[qb + 256 + (i << 2)]) = k4;
  }
}

// ------------------------- kv partials: per (b,h,chunk) 32x32 outer sum -----
__global__ __launch_bounds__(256) void k_kv_partial(
    const float* __restrict__ qkvo, float* __restrict__ kvp) {
  __shared__ float kt[32][33];
  __shared__ float vt[32][33];
  int bh = blockIdx.x, chunk = blockIdx.y;
  int b = bh >> 3, h = bh & 7;
  int t = threadIdx.x;
  int lrow = t >> 3, lc4 = (t & 7) << 2;
  int d = t >> 3, e0 = (t & 7) << 2;
  float a0 = 0, a1 = 0, a2 = 0, a3 = 0;
  int n_start = chunk << 9;                    // 512 per chunk
  for (int n0 = n_start; n0 < n_start + 512; n0 += 32) {
    size_t g = (size_t)(b * N + n0 + lrow) * C4 + (h << 5) + lc4;
    float4 k4 = *reinterpret_cast<const float4*>(&qkvo[g + 256]);
    float4 v4 = *reinterpret_cast<const float4*>(&qkvo[g + 512]);
    kt[lrow][lc4 + 0] = k4.x; kt[lrow][lc4 + 1] = k4.y;
    kt[lrow][lc4 + 2] = k4.z; kt[lrow][lc4 + 3] = k4.w;
    vt[lrow][lc4 + 0] = v4.x; vt[lrow][lc4 + 1] = v4.y;
    vt[lrow][lc4 + 2] = v4.z; vt[lrow][lc4 + 3] = v4.w;
    __syncthreads();
#pragma unroll
    for (int nn = 0; nn < 32; ++nn) {
      float kd = kt[nn][d];
      a0 = fmaf(kd, vt[nn][e0 + 0], a0);
      a1 = fmaf(kd, vt[nn][e0 + 1], a1);
      a2 = fmaf(kd, vt[nn][e0 + 2], a2);
      a3 = fmaf(kd, vt[nn][e0 + 3], a3);
    }
    __syncthreads();
  }
  size_t o = (size_t)(bh * 8 + chunk) * 1024 + (d << 5) + e0;
  kvp[o + 0] = a0; kvp[o + 1] = a1; kvp[o + 2] = a2; kvp[o + 3] = a3;
}

__global__ void k_kv_reduce(const float* __restrict__ kvp, float* __restrict__ kv,
                            int total) {
  int i = blockIdx.x * 256 + threadIdx.x;     // bpp*NH*1024
  if (i >= total) return;
  int bh = i >> 10, de = i & 1023;
  float s = 0.f;
#pragma unroll
  for (int c = 0; c < 8; ++c) s += kvp[(size_t)(bh * 8 + c) * 1024 + de];
  kv[i] = s * (1.0f / N);                     // fold inv_sqrt_n^2
}

// -------- depthwise 5x5 conv on v (LEPE) -> staged into d_out rows ----------
__global__ __launch_bounds__(256) void k_lepe(
    const float* __restrict__ qkvo, const float* __restrict__ wgt,
    const float* __restrict__ lb, float* __restrict__ lepe_out, int b0) {
  int blk = blockIdx.x;                        // bpp*64*4
  int b = blk >> 8, rem = blk & 255;
  int y = rem >> 2, x0 = (rem & 3) << 4;       // 16 pixels along x
  int c = threadIdx.x;
  float w[25];
#pragma unroll
  for (int i = 0; i < 25; ++i) w[i] = wgt[c * 25 + i];
  float bias = lb[c];
  float acc[16];
#pragma unroll
  for (int p = 0; p < 16; ++p) acc[p] = bias;
#pragma unroll
  for (int dy = 0; dy < 5; ++dy) {
    int yy = y + dy - 2;
    if (yy < 0 || yy >= IH) continue;
    size_t rowb = (size_t)(b * N + (yy << 6)) * C4 + 512 + c;
#pragma unroll
    for (int dx = 0; dx < 5; ++dx) {
      float wv = w[dy * 5 + dx];
#pragma unroll
      for (int p = 0; p < 16; ++p) {
        int xx = x0 + p + dx - 2;
        if (xx < 0 || xx >= IW) continue;
        acc[p] = fmaf(qkvo[rowb + (size_t)xx * C4], wv, acc[p]);
      }
    }
  }
#pragma unroll
  for (int p = 0; p < 16; ++p)
    lepe_out[(size_t)((b0 + b) * N + (y << 6) + x0 + p) * C + c] = acc[p];
}

// ---- opre = ((q_rope @ kv) * z + lepe) * o  -> written into qkvo q-slot ----
__global__ __launch_bounds__(256) void k_out_combine(
    float* __restrict__ qkvo, const float* __restrict__ kv,
    const float* __restrict__ z, const float* __restrict__ lepe, int b0) {
  __shared__ float kvs[1024];
  int bh = blockIdx.x, chunk = blockIdx.y;
  int b = bh >> 3, h = bh & 7;
  int t = threadIdx.x;
  reinterpret_cast<float4*>(kvs)[t] =
      reinterpret_cast<const float4*>(&kv[(size_t)bh << 10])[t];
  __syncthreads();
  int n = (chunk << 8) + t;
  size_t rowbase = (size_t)(b * N + n) * C4;
  float q[32];
#pragma unroll
  for (int i = 0; i < 8; ++i) {
    float4 q4 = *reinterpret_cast<const float4*>(&qkvo[rowbase + (h << 5) + (i << 2)]);
    q[i * 4 + 0] = q4.x; q[i * 4 + 1] = q4.y; q[i * 4 + 2] = q4.z; q[i * 4 + 3] = q4.w;
  }
  float zv = z[(size_t)bh * N + n];
  size_t oc = (size_t)((b0 + b) * N + n) * C + (h << 5);   // lepe rows in d_out
#pragma unroll
  for (int e4 = 0; e4 < 8; ++e4) {
    float ax = 0, ay = 0, az = 0, aw = 0;
#pragma unroll
    for (int dd = 0; dd < 32; ++dd) {
      float4 kv4 = *reinterpret_cast<const float4*>(&kvs[(dd << 5) + (e4 << 2)]);
      float qd = q[dd];
      ax = fmaf(qd, kv4.x, ax); ay = fmaf(qd, kv4.y, ay);
      az = fmaf(qd, kv4.z, az); aw = fmaf(qd, kv4.w, aw);
    }
    float4 lp = *reinterpret_cast<const float4*>(&lepe[oc + (e4 << 2)]);
    float4 ov = *reinterpret_cast<const float4*>(
        &qkvo[rowbase + 768 + (h << 5) + (e4 << 2)]);
    float4 r;
    r.x = (ax * zv + lp.x) * ov.x;
    r.y = (ay * zv + lp.y) * ov.y;
    r.z = (az * zv + lp.z) * ov.z;
    r.w = (aw * zv + lp.w) * ov.w;
    *reinterpret_cast<float4*>(&qkvo[rowbase + (h << 5) + (e4 << 2)]) = r;
  }
}

// ---------------------------------------------------------------------------
static inline size_t ws_bytes_needed(int bpp) {
  size_t pn = (size_t)bpp * N;
  size_t f32c = pn * C4                       // qkvo
              + (size_t)bpp * NH * HD * 2     // qmean, kmean
              + (size_t)bpp * NH * N * 2      // eff, z
              + (size_t)bpp * NH * 1024 * 8   // kvp
              + (size_t)bpp * NH * 1024       // kv
              + (size_t)bpp * NH * 16 * 32    // colmean partials
              + (size_t)N * 16 * 2;           // cos/sin
  size_t f16c = pn * C * 2                    // xh, xl
              + (size_t)C * C4 * 2            // wq T splits
              + (size_t)C * C * 2;            // wp T splits
  return f32c * 4 + f16c * 2;
}

extern "C" void kernel_launch(void* const* d_in, const int* in_sizes, int n_in,
                              void* d_out, int out_size, void* d_ws, size_t ws_size,
                              hipStream_t stream) {
  const float* x      = (const float*)d_in[0];
  const float* w_qkvo = (const float*)d_in[1];
  const float* b_qkvo = (const float*)d_in[2];
  const float* lepe_w = (const float*)d_in[3];
  const float* lepe_b = (const float*)d_in[4];
  const float* w_proj = (const float*)d_in[5];
  const float* b_proj = (const float*)d_in[6];
  float* out = (float*)d_out;
  float* ws  = (float*)d_ws;

  int bpp = 2;
  if (ws_bytes_needed(16) <= ws_size) bpp = 16;
  else if (ws_bytes_needed(8) <= ws_size) bpp = 8;
  else if (ws_bytes_needed(4) <= ws_size) bpp = 4;

  size_t pn = (size_t)bpp * N;
  float* qkvo  = ws;
  float* qmean = qkvo  + pn * C4;
  float* kmean = qmean + (size_t)bpp * NH * HD;
  float* eff   = kmean + (size_t)bpp * NH * HD;
  float* zbuf  = eff   + (size_t)bpp * NH * N;
  float* kvp   = zbuf  + (size_t)bpp * NH * N;
  float* kv    = kvp   + (size_t)bpp * NH * 1024 * 8;
  float* part  = kv    + (size_t)bpp * NH * 1024;
  float* cosT  = part  + (size_t)bpp * NH * 16 * 32;
  float* sinT  = cosT  + (size_t)N * 16;
  _Float16* xh  = (_Float16*)(sinT + (size_t)N * 16);
  _Float16* xl  = xh  + pn * C;
  _Float16* wqh = xl  + pn * C;
  _Float16* wql = wqh + (size_t)C * C4;
  _Float16* wph = wql + (size_t)C * C4;
  _Float16* wpl = wph + (size_t)C * C;

  k_tables<<<N * 16 / 256, 256, 0, stream>>>(cosT, sinT);
  k_split_wT<<<C4, 256, 0, stream>>>(w_qkvo, C4, wqh, wql);
  k_split_wT<<<C, 256, 0, stream>>>(w_proj, C, wph, wpl);

  int nbh = bpp * NH;
  for (int b0 = 0; b0 < B; b0 += bpp) {
    int tot4 = (int)(pn * C / 4);
    k_split_x<<<(tot4 + 255) / 256, 256, 0, stream>>>(x + (size_t)b0 * N * C, xh, xl, tot4);
    // GEMM1: qkvo = x@w_qkvo + b, elu on cols<512 (A preconverted)
    k_gemm_split<<<dim3(pn / 128, C4 / 128), 256, 0, stream>>>(
        xh, xl, nullptr, C, wqh, wql, b_qkvo, qkvo, C4, 512);
    k_colmean_part<<<dim3(nbh, 16), 256, 0, stream>>>(qkvo, nullptr, part, 0);
    k_colmean_fin<<<(nbh * 32 + 255) / 256, 256, 0, stream>>>(part, qmean, nbh * 32);
    k_scores<<<(nbh * N) / 256, 256, 0, stream>>>(qkvo, qmean, eff);
    k_softmax<<<nbh, 256, 0, stream>>>(eff);
    k_colmean_part<<<dim3(nbh, 16), 256, 0, stream>>>(qkvo, eff, part, 256);
    k_colmean_fin<<<(nbh * 32 + 255) / 256, 256, 0, stream>>>(part, kmean, nbh * 32);
    k_rope_z<<<(nbh * N) / 256, 256, 0, stream>>>(qkvo, eff, kmean, cosT, sinT, zbuf);
    k_kv_partial<<<dim3(nbh, 8), 256, 0, stream>>>(qkvo, kvp);
    k_kv_reduce<<<(nbh * 1024 + 255) / 256, 256, 0, stream>>>(kvp, kv, nbh * 1024);
    k_lepe<<<bpp * IH * 4, 256, 0, stream>>>(qkvo, lepe_w, lepe_b, out, b0);
    k_out_combine<<<dim3(nbh, N / 256), 256, 0, stream>>>(qkvo, kv, zbuf, out, b0);
    // GEMM2: out = opre @ w_proj + b (A = f32 opre in qkvo q-slot)
    k_gemm_split<<<dim3(pn / 128, C / 128), 256, 0, stream>>>(
        nullptr, nullptr, qkvo, C4, wph, wpl, b_proj, out + (size_t)b0 * N * C, C, 0);
  }
}

// Round 7
// 738.698 us; speedup vs baseline: 1.0608x; 1.0608x over previous
//
#include <hip/hip_runtime.h>
#include <math.h>

// RALALinearAttention on MI355X — round 7.
// r6 diagnosis: GEMM K-loop latency-serialized (loads issue after the MFMA
// barrier; MfmaUtil 21.6% ~= 240cy MFMA / ~1100cy chain). VALU staging was
// NOT binding (VALUBusy 32->16 with zero dur change) and k_split_x cost 80us.
// r7: T14 reg-prefetch pipeline (load K-step t+1 into regs under MFMA of t),
// A-split folded back into staging (cvt overlaps MFMA now), k_split_x deleted.
constexpr int B   = 16;
constexpr int IH  = 64;
constexpr int IW  = 64;
constexpr int C   = 256;
constexpr int NH  = 8;
constexpr int HD  = 32;
constexpr int N   = IH * IW;    // 4096
constexpr int C4  = 4 * C;      // 1024

using f16x8 = __attribute__((ext_vector_type(8))) _Float16;
using f32x4 = __attribute__((ext_vector_type(4))) float;

// ---------------------------------------------------------------- tables ----
__global__ void k_tables(float* __restrict__ cosT, float* __restrict__ sinT) {
  int t = blockIdx.x * 256 + threadIdx.x;      // N*16 = 65536
  int j = t & 15, pix = t >> 4;
  int y = pix >> 6, x = pix & 63;
  int jj = j & 7;
  double theta = pow(10000.0, -(double)jj / 8.0);
  double pos = (j < 8) ? (double)y : (double)x;
  double ang = pos * theta;
  cosT[t] = (float)cos(ang);
  sinT[t] = (float)sin(ang);
}

// ------------- split weight [K=256][ldb] -> transposed [ldb][256] -----------
__global__ void k_split_wT(const float* __restrict__ w, int ldb,
                           _Float16* __restrict__ hiT, _Float16* __restrict__ loT) {
  int n = blockIdx.x;           // column of w
  int k = threadIdx.x;          // 0..255
  float v = w[(size_t)k * ldb + n];
  _Float16 h = (_Float16)v;
  hiT[(size_t)n * 256 + k] = h;
  loT[(size_t)n * 256 + k] = (_Float16)(v - (float)h);
}

// --------------- split-f16 MFMA GEMM: C = A(f32) @ B + bias -----------------
// 128x128 tile, 4 waves (2x2), K=256, BK=32, 3-product Ootomo split.
// A: f32, split in staging (cvt overlaps MFMA via reg-prefetch pipeline).
// B: preconverted transposed splits [N][256].
// Epilogue: LDS transpose -> float4-coalesced C stores. nelu: elu+1 columns.
__global__ __launch_bounds__(256) void k_gemm_split(
    const float* __restrict__ A, int lda,
    const _Float16* __restrict__ BhT, const _Float16* __restrict__ BlT,
    const float* __restrict__ bias, float* __restrict__ Cm, int ldc,
    int nelu) {
  __shared__ _Float16 lds[4 * 5120];          // Ah | Al | Bh | Bl, stride 40
  _Float16* AhL = lds;
  _Float16* AlL = lds + 5120;
  _Float16* BhL = lds + 10240;
  _Float16* BlL = lds + 15360;
  int t = threadIdx.x;
  int m0 = blockIdx.x * 128, n0 = blockIdx.y * 128;
  int lane = t & 63;
  int wm = t >> 7, wn = (t >> 6) & 1;
  int lr = lane & 15, lg = lane >> 4;
  int srow = t >> 1, sseg = t & 1;            // one row-half per thread

  f32x4 acc[4][4] = {};

  // ---- prologue: prefetch kc=0 into registers ----
  const float* aP = &A[(size_t)(m0 + srow) * lda + sseg * 16];
  const _Float16* bhP = &BhT[(size_t)(n0 + srow) * 256 + sseg * 16];
  const _Float16* blP = &BlT[(size_t)(n0 + srow) * 256 + sseg * 16];
  float4 ar0 = *(const float4*)(aP + 0);
  float4 ar1 = *(const float4*)(aP + 4);
  float4 ar2 = *(const float4*)(aP + 8);
  float4 ar3 = *(const float4*)(aP + 12);
  f16x8 brh0 = *(const f16x8*)(bhP + 0);
  f16x8 brh1 = *(const f16x8*)(bhP + 8);
  f16x8 brl0 = *(const f16x8*)(blP + 0);
  f16x8 brl1 = *(const f16x8*)(blP + 8);

  for (int kc = 0; kc < 256; kc += 32) {
    // ---- convert + write current regs to LDS ----
    {
      float av[16] = {ar0.x, ar0.y, ar0.z, ar0.w, ar1.x, ar1.y, ar1.z, ar1.w,
                      ar2.x, ar2.y, ar2.z, ar2.w, ar3.x, ar3.y, ar3.z, ar3.w};
      f16x8 h0, h1, l0, l1;
#pragma unroll
      for (int j = 0; j < 8; ++j) {
        _Float16 h = (_Float16)av[j];
        h0[j] = h; l0[j] = (_Float16)(av[j] - (float)h);
        _Float16 h2 = (_Float16)av[j + 8];
        h1[j] = h2; l1[j] = (_Float16)(av[j + 8] - (float)h2);
      }
      int d = srow * 40 + sseg * 16;
      *(f16x8*)&AhL[d] = h0; *(f16x8*)&AhL[d + 8] = h1;
      *(f16x8*)&AlL[d] = l0; *(f16x8*)&AlL[d + 8] = l1;
      *(f16x8*)&BhL[d] = brh0; *(f16x8*)&BhL[d + 8] = brh1;
      *(f16x8*)&BlL[d] = brl0; *(f16x8*)&BlL[d + 8] = brl1;
    }
    __syncthreads();

    // ---- issue prefetch of next K-step (overlaps ds_read + MFMA below) ----
    if (kc + 32 < 256) {
      const float* aN = aP + kc + 32;
      const _Float16* bhN = bhP + kc + 32;
      const _Float16* blN = blP + kc + 32;
      ar0 = *(const float4*)(aN + 0);
      ar1 = *(const float4*)(aN + 4);
      ar2 = *(const float4*)(aN + 8);
      ar3 = *(const float4*)(aN + 12);
      brh0 = *(const f16x8*)(bhN + 0);
      brh1 = *(const f16x8*)(bhN + 8);
      brl0 = *(const f16x8*)(blN + 0);
      brl1 = *(const f16x8*)(blN + 8);
    }

    // ---- fragments + 48 MFMA ----
    f16x8 ah[4], al[4];
#pragma unroll
    for (int mi = 0; mi < 4; ++mi) {
      int ar = (wm * 64 + mi * 16 + lr) * 40 + lg * 8;
      ah[mi] = *(const f16x8*)&AhL[ar];
      al[mi] = *(const f16x8*)&AlL[ar];
    }
#pragma unroll
    for (int ni = 0; ni < 4; ++ni) {
      int br = (wn * 64 + ni * 16 + lr) * 40 + lg * 8;
      f16x8 bh = *(const f16x8*)&BhL[br];
      f16x8 bl = *(const f16x8*)&BlL[br];
#pragma unroll
      for (int mi = 0; mi < 4; ++mi) {
        acc[mi][ni] = __builtin_amdgcn_mfma_f32_16x16x32_f16(ah[mi], bh, acc[mi][ni], 0, 0, 0);
        acc[mi][ni] = __builtin_amdgcn_mfma_f32_16x16x32_f16(al[mi], bh, acc[mi][ni], 0, 0, 0);
        acc[mi][ni] = __builtin_amdgcn_mfma_f32_16x16x32_f16(ah[mi], bl, acc[mi][ni], 0, 0, 0);
      }
    }
    __syncthreads();
  }

  // ---- epilogue: LDS transpose -> coalesced float4 stores ----
  float* Cl = reinterpret_cast<float*>(lds);   // 32 x 132 f32 = 16.9 KB
  int ri2 = t >> 3, c0 = (t & 7) << 4;
#pragma unroll
  for (int mi = 0; mi < 4; ++mi) {
#pragma unroll
    for (int ni = 0; ni < 4; ++ni) {
      int col = wn * 64 + ni * 16 + lr;
#pragma unroll
      for (int r = 0; r < 4; ++r)
        Cl[(wm * 16 + lg * 4 + r) * 132 + col] = acc[mi][ni][r];
    }
    __syncthreads();
    int grow = m0 + (ri2 >> 4) * 64 + mi * 16 + (ri2 & 15);
#pragma unroll
    for (int j = 0; j < 4; ++j) {
      int col = n0 + c0 + j * 4;
      float4 v = *(const float4*)&Cl[ri2 * 132 + c0 + j * 4];
      float4 bb = *(const float4*)&bias[col];
      v.x += bb.x; v.y += bb.y; v.z += bb.z; v.w += bb.w;
      if (col < nelu) {
        v.x = (v.x > 0.f) ? v.x + 1.f : expf(v.x);
        v.y = (v.y > 0.f) ? v.y + 1.f : expf(v.y);
        v.z = (v.z > 0.f) ? v.z + 1.f : expf(v.z);
        v.w = (v.w > 0.f) ? v.w + 1.f : expf(v.w);
      }
      *(float4*)&Cm[(size_t)grow * ldc + col] = v;
    }
    __syncthreads();
  }
}

// ---------------- column-mean over n, stage 1: per-(bh,chunk) partials ------
__global__ __launch_bounds__(256) void k_colmean_part(
    const float* __restrict__ qkvo, const float* __restrict__ effN,
    float* __restrict__ part, int colbase) {
  int bh = blockIdx.x, chunk = blockIdx.y;
  int b = bh >> 3, h = bh & 7;
  int t = threadIdx.x;
  int d = t & 31, r = t >> 5;                  // 8 rows in flight
  size_t base = (size_t)b * N * C4 + colbase + (h << 5) + d;
  int n0 = chunk << 8;
  float acc = 0.f;
  for (int n = n0 + r; n < n0 + 256; n += 8) {
    float v = qkvo[base + (size_t)n * C4];
    if (effN) v *= effN[(size_t)bh * N + n];
    acc += v;
  }
  __shared__ float sm[256];
  sm[t] = acc;
  __syncthreads();
  if (t < 32) {
    float s = 0.f;
#pragma unroll
    for (int rr = 0; rr < 8; ++rr) s += sm[rr * 32 + t];
    part[(size_t)((bh << 4) + chunk) * 32 + t] = s;
  }
}

// ---------------- column-mean stage 2: combine 16 chunk partials ------------
__global__ void k_colmean_fin(const float* __restrict__ part,
                              float* __restrict__ outm, int total) {
  int i = blockIdx.x * 256 + threadIdx.x;      // bpp*NH*32
  if (i >= total) return;
  int bh = i >> 5, d = i & 31;
  float s = 0.f;
#pragma unroll
  for (int c = 0; c < 16; ++c) s += part[(size_t)((bh << 4) + c) * 32 + d];
  outm[i] = s * (1.0f / N);
}

// ------------------------------------------- scores s = scale * qmean.k -----
__global__ void k_scores(const float* __restrict__ qkvo,
                         const float* __restrict__ qmean, float* __restrict__ s) {
  int tid = blockIdx.x * 256 + threadIdx.x;   // bpp*NH*N
  int n = tid & (N - 1);
  int bh = tid >> 12;
  int b = bh >> 3, h = bh & 7;
  const float* kp = &qkvo[(size_t)(b * N + n) * C4 + 256 + (h << 5)];
  const float* qm = &qmean[bh << 5];
  float dot = 0.f;
#pragma unroll
  for (int i = 0; i < 8; ++i) {
    float4 k4 = *reinterpret_cast<const float4*>(&kp[i << 2]);
    float4 q4 = *reinterpret_cast<const float4*>(&qm[i << 2]);
    dot += k4.x * q4.x + k4.y * q4.y + k4.z * q4.z + k4.w * q4.w;
  }
  s[tid] = dot * 0.1767766952966369f;         // 32^-0.5
}

// ------------- softmax over n (LDS-cached row), fold *N (eff -> eff*N) ------
__global__ __launch_bounds__(256) void k_softmax(float* __restrict__ s) {
  __shared__ float rowl[N];
  __shared__ float red[256];
  int bh = blockIdx.x;
  int t = threadIdx.x;
  float* row = s + (size_t)bh * N;
  float mx = -3.4e38f;
  for (int i = t; i < N / 4; i += 256) {
    float4 v = reinterpret_cast<const float4*>(row)[i];
    reinterpret_cast<float4*>(rowl)[i] = v;
    mx = fmaxf(mx, fmaxf(fmaxf(v.x, v.y), fmaxf(v.z, v.w)));
  }
  red[t] = mx; __syncthreads();
  for (int off = 128; off > 0; off >>= 1) {
    if (t < off) red[t] = fmaxf(red[t], red[t + off]);
    __syncthreads();
  }
  mx = red[0]; __syncthreads();
  float sum = 0.f;
  for (int n = t; n < N; n += 256) {
    float e = expf(rowl[n] - mx);
    rowl[n] = e;
    sum += e;
  }
  red[t] = sum; __syncthreads();
  for (int off = 128; off > 0; off >>= 1) {
    if (t < off) red[t] += red[t + off];
    __syncthreads();
  }
  float scale = (float)N / red[0];
  for (int i = t; i < N / 4; i += 256) {
    float4 v = reinterpret_cast<const float4*>(rowl)[i];
    v.x *= scale; v.y *= scale; v.z *= scale; v.w *= scale;
    reinterpret_cast<float4*>(row)[i] = v;
  }
}

// ---------------- z + scale k by eff*N + RoPE(q,k) in place + write z -------
__global__ __launch_bounds__(256) void k_rope_z(
    float* __restrict__ qkvo, const float* __restrict__ effN,
    const float* __restrict__ kmean, const float* __restrict__ cosT,
    const float* __restrict__ sinT, float* __restrict__ z) {
  int tid = blockIdx.x * 256 + threadIdx.x;   // bpp*N*NH
  int h = tid & 7;
  int bn = tid >> 3;                          // pass-local row
  int n = bn & (N - 1);
  int b = bn >> 12;
  size_t qb = (size_t)bn * C4 + (h << 5);
  float q[32], k[32];
#pragma unroll
  for (int i = 0; i < 8; ++i) {
    float4 q4 = *reinterpret_cast<const float4*>(&qkvo[qb + (i << 2)]);
    float4 k4 = *reinterpret_cast<const float4*>(&qkvo[qb + 256 + (i << 2)]);
    q[i * 4 + 0] = q4.x; q[i * 4 + 1] = q4.y; q[i * 4 + 2] = q4.z; q[i * 4 + 3] = q4.w;
    k[i * 4 + 0] = k4.x; k[i * 4 + 1] = k4.y; k[i * 4 + 2] = k4.z; k[i * 4 + 3] = k4.w;
  }
  int bh = (b << 3) + h;
  const float* km = &kmean[bh << 5];
  float dot = 0.f;
#pragma unroll
  for (int dd = 0; dd < 32; ++dd) dot += q[dd] * km[dd];
  z[(size_t)bh * N + n] = 1.0f / (dot + 1e-6f);
  float ef = effN[(size_t)bh * N + n];
#pragma unroll
  for (int dd = 0; dd < 32; ++dd) k[dd] *= ef;
  const float* cp = &cosT[n << 4];
  const float* sp = &sinT[n << 4];
#pragma unroll
  for (int j = 0; j < 16; ++j) {
    float cc = cp[j], ss = sp[j];
    float qr = q[2 * j], qi = q[2 * j + 1];
    q[2 * j]     = qr * cc - qi * ss;
    q[2 * j + 1] = qr * ss + qi * cc;
    float kr = k[2 * j], ki = k[2 * j + 1];
    k[2 * j]     = kr * cc - ki * ss;
    k[2 * j + 1] = kr * ss + ki * cc;
  }
#pragma unroll
  for (int i = 0; i < 8; ++i) {
    float4 q4 = {q[i * 4 + 0], q[i * 4 + 1], q[i * 4 + 2], q[i * 4 + 3]};
    float4 k4 = {k[i * 4 + 0], k[i * 4 + 1], k[i * 4 + 2], k[i * 4 + 3]};
    *reinterpret_cast<float4*>(&qkvo[qb + (i << 2)]) = q4;
    *reinterpret_cast<float4*>(&qkvo[qb + 256 + (i << 2)]) = k4;
  }
}

// ------------------------- kv partials: per (b,h,chunk) 32x32 outer sum -----
__global__ __launch_bounds__(256) void k_kv_partial(
    const float* __restrict__ qkvo, float* __restrict__ kvp) {
  __shared__ float kt[32][33];
  __shared__ float vt[32][33];
  int bh = blockIdx.x, chunk = blockIdx.y;
  int b = bh >> 3, h = bh & 7;
  int t = threadIdx.x;
  int lrow = t >> 3, lc4 = (t & 7) << 2;
  int d = t >> 3, e0 = (t & 7) << 2;
  float a0 = 0, a1 = 0, a2 = 0, a3 = 0;
  int n_start = chunk << 9;                    // 512 per chunk
  for (int n0 = n_start; n0 < n_start + 512; n0 += 32) {
    size_t g = (size_t)(b * N + n0 + lrow) * C4 + (h << 5) + lc4;
    float4 k4 = *reinterpret_cast<const float4*>(&qkvo[g + 256]);
    float4 v4 = *reinterpret_cast<const float4*>(&qkvo[g + 512]);
    kt[lrow][lc4 + 0] = k4.x; kt[lrow][lc4 + 1] = k4.y;
    kt[lrow][lc4 + 2] = k4.z; kt[lrow][lc4 + 3] = k4.w;
    vt[lrow][lc4 + 0] = v4.x; vt[lrow][lc4 + 1] = v4.y;
    vt[lrow][lc4 + 2] = v4.z; vt[lrow][lc4 + 3] = v4.w;
    __syncthreads();
#pragma unroll
    for (int nn = 0; nn < 32; ++nn) {
      float kd = kt[nn][d];
      a0 = fmaf(kd, vt[nn][e0 + 0], a0);
      a1 = fmaf(kd, vt[nn][e0 + 1], a1);
      a2 = fmaf(kd, vt[nn][e0 + 2], a2);
      a3 = fmaf(kd, vt[nn][e0 + 3], a3);
    }
    __syncthreads();
  }
  size_t o = (size_t)(bh * 8 + chunk) * 1024 + (d << 5) + e0;
  kvp[o + 0] = a0; kvp[o + 1] = a1; kvp[o + 2] = a2; kvp[o + 3] = a3;
}

__global__ void k_kv_reduce(const float* __restrict__ kvp, float* __restrict__ kv,
                            int total) {
  int i = blockIdx.x * 256 + threadIdx.x;     // bpp*NH*1024
  if (i >= total) return;
  int bh = i >> 10, de = i & 1023;
  float s = 0.f;
#pragma unroll
  for (int c = 0; c < 8; ++c) s += kvp[(size_t)(bh * 8 + c) * 1024 + de];
  kv[i] = s * (1.0f / N);                     // fold inv_sqrt_n^2
}

// -------- depthwise 5x5 conv on v (LEPE) -> staged into d_out rows ----------
__global__ __launch_bounds__(256) void k_lepe(
    const float* __restrict__ qkvo, const float* __restrict__ wgt,
    const float* __restrict__ lb, float* __restrict__ lepe_out, int b0) {
  int blk = blockIdx.x;                        // bpp*64*4
  int b = blk >> 8, rem = blk & 255;
  int y = rem >> 2, x0 = (rem & 3) << 4;       // 16 pixels along x
  int c = threadIdx.x;
  float w[25];
#pragma unroll
  for (int i = 0; i < 25; ++i) w[i] = wgt[c * 25 + i];
  float bias = lb[c];
  float acc[16];
#pragma unroll
  for (int p = 0; p < 16; ++p) acc[p] = bias;
#pragma unroll
  for (int dy = 0; dy < 5; ++dy) {
    int yy = y + dy - 2;
    if (yy < 0 || yy >= IH) continue;
    size_t rowb = (size_t)(b * N + (yy << 6)) * C4 + 512 + c;
#pragma unroll
    for (int dx = 0; dx < 5; ++dx) {
      float wv = w[dy * 5 + dx];
#pragma unroll
      for (int p = 0; p < 16; ++p) {
        int xx = x0 + p + dx - 2;
        if (xx < 0 || xx >= IW) continue;
        acc[p] = fmaf(qkvo[rowb + (size_t)xx * C4], wv, acc[p]);
      }
    }
  }
#pragma unroll
  for (int p = 0; p < 16; ++p)
    lepe_out[(size_t)((b0 + b) * N + (y << 6) + x0 + p) * C + c] = acc[p];
}

// ---- opre = ((q_rope @ kv) * z + lepe) * o  -> written into qkvo q-slot ----
__global__ __launch_bounds__(256) void k_out_combine(
    float* __restrict__ qkvo, const float* __restrict__ kv,
    const float* __restrict__ z, const float* __restrict__ lepe, int b0) {
  __shared__ float kvs[1024];
  int bh = blockIdx.x, chunk = blockIdx.y;
  int b = bh >> 3, h = bh & 7;
  int t = threadIdx.x;
  reinterpret_cast<float4*>(kvs)[t] =
      reinterpret_cast<const float4*>(&kv[(size_t)bh << 10])[t];
  __syncthreads();
  int n = (chunk << 8) + t;
  size_t rowbase = (size_t)(b * N + n) * C4;
  float q[32];
#pragma unroll
  for (int i = 0; i < 8; ++i) {
    float4 q4 = *reinterpret_cast<const float4*>(&qkvo[rowbase + (h << 5) + (i << 2)]);
    q[i * 4 + 0] = q4.x; q[i * 4 + 1] = q4.y; q[i * 4 + 2] = q4.z; q[i * 4 + 3] = q4.w;
  }
  float zv = z[(size_t)bh * N + n];
  size_t oc = (size_t)((b0 + b) * N + n) * C + (h << 5);   // lepe rows in d_out
#pragma unroll
  for (int e4 = 0; e4 < 8; ++e4) {
    float ax = 0, ay = 0, az = 0, aw = 0;
#pragma unroll
    for (int dd = 0; dd < 32; ++dd) {
      float4 kv4 = *reinterpret_cast<const float4*>(&kvs[(dd << 5) + (e4 << 2)]);
      float qd = q[dd];
      ax = fmaf(qd, kv4.x, ax); ay = fmaf(qd, kv4.y, ay);
      az = fmaf(qd, kv4.z, az); aw = fmaf(qd, kv4.w, aw);
    }
    float4 lp = *reinterpret_cast<const float4*>(&lepe[oc + (e4 << 2)]);
    float4 ov = *reinterpret_cast<const float4*>(
        &qkvo[rowbase + 768 + (h << 5) + (e4 << 2)]);
    float4 r;
    r.x = (ax * zv + lp.x) * ov.x;
    r.y = (ay * zv + lp.y) * ov.y;
    r.z = (az * zv + lp.z) * ov.z;
    r.w = (aw * zv + lp.w) * ov.w;
    *reinterpret_cast<float4*>(&qkvo[rowbase + (h << 5) + (e4 << 2)]) = r;
  }
}

// ---------------------------------------------------------------------------
static inline size_t ws_bytes_needed(int bpp) {
  size_t pn = (size_t)bpp * N;
  size_t f32c = pn * C4                       // qkvo
              + (size_t)bpp * NH * HD * 2     // qmean, kmean
              + (size_t)bpp * NH * N * 2      // eff, z
              + (size_t)bpp * NH * 1024 * 8   // kvp
              + (size_t)bpp * NH * 1024       // kv
              + (size_t)bpp * NH * 16 * 32    // colmean partials
              + (size_t)N * 16 * 2;           // cos/sin
  size_t f16c = (size_t)C * C4 * 2            // wq T splits
              + (size_t)C * C * 2;            // wp T splits
  return f32c * 4 + f16c * 2;
}

extern "C" void kernel_launch(void* const* d_in, const int* in_sizes, int n_in,
                              void* d_out, int out_size, void* d_ws, size_t ws_size,
                              hipStream_t stream) {
  const float* x      = (const float*)d_in[0];
  const float* w_qkvo = (const float*)d_in[1];
  const float* b_qkvo = (const float*)d_in[2];
  const float* lepe_w = (const float*)d_in[3];
  const float* lepe_b = (const float*)d_in[4];
  const float* w_proj = (const float*)d_in[5];
  const float* b_proj = (const float*)d_in[6];
  float* out = (float*)d_out;
  float* ws  = (float*)d_ws;

  int bpp = 2;
  if (ws_bytes_needed(16) <= ws_size) bpp = 16;
  else if (ws_bytes_needed(8) <= ws_size) bpp = 8;
  else if (ws_bytes_needed(4) <= ws_size) bpp = 4;

  size_t pn = (size_t)bpp * N;
  float* qkvo  = ws;
  float* qmean = qkvo  + pn * C4;
  float* kmean = qmean + (size_t)bpp * NH * HD;
  float* eff   = kmean + (size_t)bpp * NH * HD;
  float* zbuf  = eff   + (size_t)bpp * NH * N;
  float* kvp   = zbuf  + (size_t)bpp * NH * N;
  float* kv    = kvp   + (size_t)bpp * NH * 1024 * 8;
  float* part  = kv    + (size_t)bpp * NH * 1024;
  float* cosT  = part  + (size_t)bpp * NH * 16 * 32;
  float* sinT  = cosT  + (size_t)N * 16;
  _Float16* wqh = (_Float16*)(sinT + (size_t)N * 16);
  _Float16* wql = wqh + (size_t)C * C4;
  _Float16* wph = wql + (size_t)C * C4;
  _Float16* wpl = wph + (size_t)C * C;

  k_tables<<<N * 16 / 256, 256, 0, stream>>>(cosT, sinT);
  k_split_wT<<<C4, 256, 0, stream>>>(w_qkvo, C4, wqh, wql);
  k_split_wT<<<C, 256, 0, stream>>>(w_proj, C, wph, wpl);

  int nbh = bpp * NH;
  for (int b0 = 0; b0 < B; b0 += bpp) {
    // GEMM1: qkvo = x@w_qkvo + b, elu on cols<512
    k_gemm_split<<<dim3(pn / 128, C4 / 128), 256, 0, stream>>>(
        x + (size_t)b0 * N * C, C, wqh, wql, b_qkvo, qkvo, C4, 512);
    k_colmean_part<<<dim3(nbh, 16), 256, 0, stream>>>(qkvo, nullptr, part, 0);
    k_colmean_fin<<<(nbh * 32 + 255) / 256, 256, 0, stream>>>(part, qmean, nbh * 32);
    k_scores<<<(nbh * N) / 256, 256, 0, stream>>>(qkvo, qmean, eff);
    k_softmax<<<nbh, 256, 0, stream>>>(eff);
    k_colmean_part<<<dim3(nbh, 16), 256, 0, stream>>>(qkvo, eff, part, 256);
    k_colmean_fin<<<(nbh * 32 + 255) / 256, 256, 0, stream>>>(part, kmean, nbh * 32);
    k_rope_z<<<(nbh * N) / 256, 256, 0, stream>>>(qkvo, eff, kmean, cosT, sinT, zbuf);
    k_kv_partial<<<dim3(nbh, 8), 256, 0, stream>>>(qkvo, kvp);
    k_kv_reduce<<<(nbh * 1024 + 255) / 256, 256, 0, stream>>>(kvp, kv, nbh * 1024);
    k_lepe<<<bpp * IH * 4, 256, 0, stream>>>(qkvo, lepe_w, lepe_b, out, b0);
    k_out_combine<<<dim3(nbh, N / 256), 256, 0, stream>>>(qkvo, kv, zbuf, out, b0);
    // GEMM2: out = opre @ w_proj + b (A = f32 opre in qkvo q-slot)
    k_gemm_split<<<dim3(pn / 128, C / 128), 256, 0, stream>>>(
        qkvo, C4, wph, wpl, b_proj, out + (size_t)b0 * N * C, C, 0);
  }
}